// Round 6
// baseline (1676.103 us; speedup 1.0000x reference)
//
#include <hip/hip_runtime.h>

// Graph-transformer layer, MI355X. N nodes, E edges, H=128, 4 heads x d=32.
// R6: k_edge reg-staged 2-deep pipeline with NAMED scalar staging vars
// (R5's ref-array staging was demoted to scratch: VGPR=64, +700MB FETCH).
// YK/YV merged into interleaved YKV[node] (512B) and prefetched with the
// hE tile 2 tiles ahead; edata(t+2) loaded at tile top, consumed at tile
// bottom. No vmcnt(0) drains. Q[row] stays sync (sorted rows -> L1 hits).

typedef __bf16 bf16x8 __attribute__((ext_vector_type(8)));
typedef float f32x4 __attribute__((ext_vector_type(4)));
typedef unsigned short u16x8 __attribute__((ext_vector_type(8)));

#define DEV static __device__ __forceinline__
#define ET 32   // edges per k_edge tile

DEV unsigned short f2b(float f){
  union { float f; unsigned u; } v; v.f = f;
  unsigned r = (v.u + 0x7FFFu + ((v.u >> 16) & 1u)) >> 16;   // RNE
  return (unsigned short)r;
}
DEV float b2f(unsigned short h){
  union { unsigned u; float f; } v; v.u = ((unsigned)h) << 16; return v.f;
}
DEV f32x4 mfma16(bf16x8 a, bf16x8 b, f32x4 c){
  return __builtin_amdgcn_mfma_f32_16x16x32_bf16(a, b, c, 0, 0, 0);
}
DEV u16x8 pack8(float4 a, float4 b){
  u16x8 p;
  p[0]=f2b(a.x); p[1]=f2b(a.y); p[2]=f2b(a.z); p[3]=f2b(a.w);
  p[4]=f2b(b.x); p[5]=f2b(b.y); p[6]=f2b(b.z); p[7]=f2b(b.w);
  return p;
}
DEV float sspf(float x){  // shifted softplus
  return fmaxf(x, 0.f) + log1pf(expf(-fabsf(x))) - 0.69314718055994531f;
}
DEV int idx64probe(const int* __restrict__ ei){
  return (ei[1] | ei[3] | ei[5] | ei[7] | ei[9]) == 0;
}
DEV int ld_row(const int* __restrict__ ei, long eg, long E, int is64, int N){
  int v = is64 ? ei[2*eg] : ei[eg];
  return min(max(v, 0), N - 1);
}
DEV int ld_col(const int* __restrict__ ei, long eg, long E, int is64, int N){
  int v = is64 ? ei[2*(E + eg)] : ei[E + eg];
  return min(max(v, 0), N - 1);
}
DEV unsigned swz(unsigned byteoff, unsigned row){
  return byteoff ^ ((row & 7u) << 4);
}
DEV void bar_lds(){
  asm volatile("s_waitcnt lgkmcnt(0)" ::: "memory");
  __builtin_amdgcn_s_barrier();
}

// ---- 128x128 MFMA tile helper (nodeprep / post): A in LDS (swizzled) ----
DEV void mma128(const unsigned short* At, const unsigned short* __restrict__ WT,
                int t, f32x4 (&acc)[4][4]){
  const int l = t & 63;
  const int wm = (t >> 7) & 1, wn = (t >> 6) & 1;
#pragma unroll
  for (int m = 0; m < 4; ++m)
#pragma unroll
    for (int n = 0; n < 4; ++n)
      acc[m][n] = f32x4{0.f, 0.f, 0.f, 0.f};
#pragma unroll
  for (int kk = 0; kk < 4; ++kk){
    bf16x8 a[4], b[4];
#pragma unroll
    for (int m = 0; m < 4; ++m){
      int row = wm*64 + m*16 + (l & 15);
      a[m] = *(const bf16x8*)((const char*)At +
              swz((unsigned)(row*256 + kk*64 + ((l >> 4) & 3)*16), (unsigned)row));
    }
#pragma unroll
    for (int n = 0; n < 4; ++n){
      int col = wn*64 + n*16 + (l & 15);
      b[n] = *(const bf16x8*)(WT + col*128 + kk*32 + ((l >> 4) & 3)*8);
    }
#pragma unroll
    for (int m = 0; m < 4; ++m)
#pragma unroll
      for (int n = 0; n < 4; ++n)
        acc[m][n] = mfma16(a[m], b[n], acc[m][n]);
  }
}

// ---- 32x128 MFMA (edge tiles): waves 2M x 2N, each 16 rows x 64 cols ----
DEV void mma32(const unsigned short* Ab, const unsigned short* __restrict__ WT,
               int t, f32x4 (&acc)[4]){
  const int l = t & 63, wid = t >> 6, wm = wid >> 1, wn = wid & 1;
#pragma unroll
  for (int n = 0; n < 4; ++n) acc[n] = f32x4{0.f, 0.f, 0.f, 0.f};
#pragma unroll
  for (int kk = 0; kk < 4; ++kk){
    int row = wm*16 + (l & 15);
    bf16x8 a = *(const bf16x8*)((const char*)Ab +
        swz((unsigned)(row*256 + kk*64 + ((l >> 4) & 3)*16), (unsigned)row));
#pragma unroll
    for (int n = 0; n < 4; ++n){
      int col = wn*64 + n*16 + (l & 15);
      bf16x8 b = *(const bf16x8*)(WT + col*128 + kk*32 + ((l >> 4) & 3)*8);
      acc[n] = mfma16(a, b, acc[n]);
    }
  }
}
DEV void store_acc32(unsigned short* Kt, const f32x4 (&acc)[4], int t){
  const int l = t & 63, wid = t >> 6, wm = wid >> 1, wn = wid & 1;
#pragma unroll
  for (int n = 0; n < 4; ++n)
#pragma unroll
    for (int reg = 0; reg < 4; ++reg){
      int er = wm*16 + ((l >> 4) & 3)*4 + reg;
      int col = wn*64 + n*16 + (l & 15);
      *(unsigned short*)((char*)Kt + swz((unsigned)(er*256 + col*2), (unsigned)er))
          = f2b(acc[n][reg]);
    }
}

__global__ void k_zero(float4* __restrict__ p, long n){
  long i = (long)blockIdx.x * blockDim.x + threadIdx.x;
  const long st = (long)gridDim.x * blockDim.x;
  const float4 z = {0.f, 0.f, 0.f, 0.f};
  for (; i < n; i += st) p[i] = z;
}

// ---- weight prep: fp32 [k][n] -> bf16 [n][k] blobs ----
__global__ void k_wprep(const float* __restrict__ WQ, const float* __restrict__ WK,
                        const float* __restrict__ WV, const float* __restrict__ WO,
                        const float* __restrict__ Wi, const float* __restrict__ Wo2,
                        unsigned short* WQT, unsigned short* WKtT, unsigned short* WKbT,
                        unsigned short* WVtT, unsigned short* WVbT, unsigned short* WOT,
                        unsigned short* WinT, unsigned short* WouT){
  int id = blockIdx.x * 256 + threadIdx.x;
  int n = id >> 7, k = id & 127;
  int d = n * 128 + k;
  WQT[d]  = f2b(WQ[k*128 + n]);
  WKtT[d] = f2b(WK[k*128 + n]);
  WKbT[d] = f2b(WK[(k+128)*128 + n]);
  WVtT[d] = f2b(WV[k*128 + n]);
  WVbT[d] = f2b(WV[(k+128)*128 + n]);
  WOT[d]  = f2b(WO[k*128 + n]);
  WinT[d] = f2b(Wi[k*128 + n]);
  WouT[d] = f2b(Wo2[k*128 + n]);
}

// ---- counting sort by destination row ----
__global__ void k_hist(const int* __restrict__ ei, int* __restrict__ cnt, long E, int N){
  const int is64 = idx64probe(ei);
  long i = (long)blockIdx.x * blockDim.x + threadIdx.x;
  const long st = (long)gridDim.x * blockDim.x;
  for (; i < E; i += st) atomicAdd(&cnt[ld_row(ei, i, E, is64, N)], 1);
}

DEV int wave_incl_scan(int v, int lane){
#pragma unroll
  for (int ofs = 1; ofs < 64; ofs <<= 1){
    int u = __shfl_up(v, ofs, 64);
    if (lane >= ofs) v += u;
  }
  return v;
}

// chunked exclusive scan: cnt -> cursor; also writes edata sentinels
__global__ __launch_bounds__(1024) void k_scan(const int* __restrict__ cnt,
                                               int* __restrict__ cursor,
                                               int4* __restrict__ edata,
                                               long E, int N){
  __shared__ int wsum[16], woff[16];
  const int t = threadIdx.x, lane = t & 63, w = t >> 6;
  const int C = (N + 1023) / 1024;
  const int base = t * C;
  int s = 0;
  for (int j = 0; j < C; ++j) if (base + j < N) s += cnt[base + j];
  int incl = wave_incl_scan(s, lane);
  if (lane == 63) wsum[w] = incl;
  __syncthreads();
  if (t == 0){
    int run = 0;
#pragma unroll
    for (int i = 0; i < 16; ++i){ woff[i] = run; run += wsum[i]; }
  }
  __syncthreads();
  int run = woff[w] + incl - s;
  for (int j = 0; j < C; ++j)
    if (base + j < N){ cursor[base + j] = run; run += cnt[base + j]; }
  // edata sentinels: [0] and [E+1 .. E+36] get row = -2
  if (t < 37){
    long gi = (t == 0) ? 0 : (E + t);
    edata[gi] = make_int4(0, -2, 0, 0);
  }
}

__global__ void k_scatter(const int* __restrict__ ei, int* __restrict__ cursor,
                          int4* __restrict__ edata, long E, int N){
  const int is64 = idx64probe(ei);
  long i = (long)blockIdx.x * blockDim.x + threadIdx.x;
  const long st = (long)gridDim.x * blockDim.x;
  for (; i < E; i += st){
    int r = ld_row(ei, i, E, is64, N);
    int c = ld_col(ei, i, E, is64, N);
    int pos = atomicAdd(&cursor[r], 1);
    edata[1 + (long)pos] = make_int4((int)i, r, c, 0);
  }
}

// ---- node prep: LN1(h_V) -> y ; Q=y@WQ ; YKV interleaved = {y@WKb, y@WVb} ----
__global__ __launch_bounds__(256) void k_nodeprep(
    const float* __restrict__ hV, const float* __restrict__ l1s, const float* __restrict__ l1b,
    const unsigned short* __restrict__ WQT, const unsigned short* __restrict__ WKbT,
    const unsigned short* __restrict__ WVbT,
    unsigned short* __restrict__ Qbf, unsigned short* __restrict__ YKVbf, int N){
  __shared__ unsigned short At[128*128];
  __shared__ float ps[256], pss[256];
  __shared__ float scs[128], bis[128];
  const int t = threadIdx.x;
  if (t < 128){ scs[t] = l1s[t]; bis[t] = l1b[t]; }
  const int r0 = blockIdx.x * 128;
  const int rl = t & 127, hf = t >> 7;
  const int r = r0 + rl;
  const float4* xp = (const float4*)(hV + (size_t)r*128 + hf*64);
  float s = 0.f, ss = 0.f;
  if (r < N){
#pragma unroll
    for (int i = 0; i < 16; ++i){
      float4 v = xp[i];
      s  += (v.x + v.y) + (v.z + v.w);
      ss += (v.x*v.x + v.y*v.y) + (v.z*v.z + v.w*v.w);
    }
  }
  ps[t] = s; pss[t] = ss;
  __syncthreads();
  const float mu  = (ps[t] + ps[t ^ 128]) * 0.0078125f;
  const float var = (pss[t] + pss[t ^ 128]) * 0.0078125f - mu*mu;
  const float rs  = rsqrtf(var + 1e-5f);
#pragma unroll
  for (int i = 0; i < 8; ++i){
    const int c = hf*64 + i*8;
    u16x8 p = {0,0,0,0,0,0,0,0};
    if (r < N){
      float4 v0 = xp[2*i], v1 = xp[2*i+1];
      p[0] = f2b((v0.x - mu)*rs*scs[c+0] + bis[c+0]);
      p[1] = f2b((v0.y - mu)*rs*scs[c+1] + bis[c+1]);
      p[2] = f2b((v0.z - mu)*rs*scs[c+2] + bis[c+2]);
      p[3] = f2b((v0.w - mu)*rs*scs[c+3] + bis[c+3]);
      p[4] = f2b((v1.x - mu)*rs*scs[c+4] + bis[c+4]);
      p[5] = f2b((v1.y - mu)*rs*scs[c+5] + bis[c+5]);
      p[6] = f2b((v1.z - mu)*rs*scs[c+6] + bis[c+6]);
      p[7] = f2b((v1.w - mu)*rs*scs[c+7] + bis[c+7]);
    }
    *(u16x8*)((char*)At + swz((unsigned)(rl*256 + c*2), (unsigned)rl)) = p;
  }
  __syncthreads();
  const int l = t & 63, wm = (t >> 7) & 1, wn = (t >> 6) & 1;
  f32x4 acc[4][4];
  for (int g = 0; g < 3; ++g){
    const unsigned short* WT = (g == 0) ? WQT : (g == 1) ? WKbT : WVbT;
    mma128(At, WT, t, acc);
#pragma unroll
    for (int m = 0; m < 4; ++m)
#pragma unroll
      for (int reg = 0; reg < 4; ++reg){
        int row = wm*64 + m*16 + ((l >> 4) & 3)*4 + reg;
        int gr = r0 + row;
        if (gr < N){
#pragma unroll
          for (int n = 0; n < 4; ++n){
            int col = wn*64 + n*16 + (l & 15);
            unsigned short v = f2b(acc[m][n][reg]);
            if (g == 0)      Qbf[(size_t)gr*128 + col] = v;
            else if (g == 1) YKVbf[(size_t)gr*256 + col] = v;
            else             YKVbf[(size_t)gr*256 + 128 + col] = v;
          }
        }
      }
  }
}

// ---- persistent fused edge pass: named-reg 2-deep pipeline ----
// Per tile: [top] load edata(t+2); convert staged hE(t) -> Ab; K MFMA;
// logits w/ staged YK(t); V MFMA; V += staged YV(t); walk; [bottom] issue
// hE/YKV loads for t+2 using edata(t+2).
__global__ __launch_bounds__(256, 4) void k_edge(
    const float* __restrict__ hE,
    const unsigned short* __restrict__ WKtT, const unsigned short* __restrict__ WVtT,
    const unsigned short* __restrict__ Qbf, const unsigned short* __restrict__ YKVbf,
    const int4* __restrict__ edata,     // [1 + E + 37], row sentinels at ends
    float* __restrict__ num, float* __restrict__ den,
    long E, long NT){
  __shared__ unsigned short Ab[ET*128];   // 8KB bf16 swizzled h_E tile
  __shared__ unsigned short Kt[ET*128];   // 8KB (K tile, then V tile)
  __shared__ float aS[ET][4];
  __shared__ int rowsT[ET + 2];           // rows of edges e0-1 .. e0+ET

  const int t = threadIdx.x;
  const int er = t >> 3, s = t & 7;       // 8 threads per edge
  const long b0 = blockIdx.x, G = gridDim.x;
  const long ntloc = (b0 < NT) ? ((NT - 1 - b0) / G + 1) : 0;
  if (ntloc == 0) return;

#define TILEOF(i) ((b0 + (i)*G < NT) ? (b0 + (i)*G) : (NT - 1))

// load staging set for the edge described by ED (value must be resident)
#define LOAD_SET(ED, H0,H1,H2,H3, K0,K1,V0,V1) do {                        \
    long pe_ = (long)(ED).x; pe_ = pe_ < 0 ? 0 : (pe_ >= E ? E - 1 : pe_); \
    const float4* hs_ = (const float4*)(hE + (size_t)pe_*128 + s*16);      \
    H0 = hs_[0]; H1 = hs_[1]; H2 = hs_[2]; H3 = hs_[3];                    \
    int ca_ = max((ED).z, 0);                                              \
    const u16x8* kp_ = (const u16x8*)(YKVbf + (size_t)ca_*256 + s*16);     \
    K0 = kp_[0]; K1 = kp_[1];                                              \
    const u16x8* vp_ = (const u16x8*)(YKVbf + (size_t)ca_*256 + 128 + s*16);\
    V0 = vp_[0]; V1 = vp_[1];                                              \
  } while(0)

#define PROC(IT, EC, H0,H1,H2,H3, K0,K1,V0,V1) do {                        \
    const int rowC_ = (EC).y;                                              \
    EC = edata[1 + TILEOF((IT) + 2)*ET + er];      /* issue early */       \
    *(u16x8*)((char*)Ab + swz((unsigned)(er*256 + s*32), (unsigned)er))    \
        = pack8(H0, H1);                                                   \
    *(u16x8*)((char*)Ab + swz((unsigned)(er*256 + s*32 + 16), (unsigned)er))\
        = pack8(H2, H3);                                                   \
    bar_lds();                                                             \
    { f32x4 acc_[4]; mma32(Ab, WKtT, t, acc_); store_acc32(Kt, acc_, t); } \
    bar_lds();                                                             \
    { int ra_ = max(rowC_, 0);                                             \
      const u16x8* qp_ = (const u16x8*)(Qbf + (size_t)ra_*128 + s*16);     \
      u16x8 q0_ = qp_[0], q1_ = qp_[1];                                    \
      u16x8 c0_ = *(const u16x8*)((const char*)Kt +                        \
          swz((unsigned)(er*256 + s*32), (unsigned)er));                   \
      u16x8 c1_ = *(const u16x8*)((const char*)Kt +                        \
          swz((unsigned)(er*256 + s*32 + 16), (unsigned)er));              \
      float pl_ = 0.f;                                                     \
      _Pragma("unroll")                                                    \
      for (int j = 0; j < 8; ++j)                                          \
        pl_ += b2f(q0_[j]) * (b2f(c0_[j]) + b2f(K0[j]));                   \
      _Pragma("unroll")                                                    \
      for (int j = 0; j < 8; ++j)                                          \
        pl_ += b2f(q1_[j]) * (b2f(c1_[j]) + b2f(K1[j]));                   \
      float full_ = pl_ + __shfl_xor(pl_, 1);                              \
      if (!(s & 1)) aS[er][s >> 1] = (rowC_ >= 0) ? expf(full_) : 0.f;     \
      if (s == 0) rowsT[1 + er] = rowC_;                                   \
      if (t == 0){                                                         \
        long base_ = TILEOF(IT)*ET;                                        \
        rowsT[0]      = edata[base_].y;                                    \
        rowsT[1 + ET] = edata[1 + base_ + ET].y;                           \
      }                                                                    \
    }                                                                      \
    bar_lds();                                                             \
    { f32x4 acc_[4]; mma32(Ab, WVtT, t, acc_); store_acc32(Kt, acc_, t); } \
    bar_lds();                                                             \
    { u16x8* p0_ = (u16x8*)((char*)Kt +                                    \
          swz((unsigned)(er*256 + s*32), (unsigned)er));                   \
      u16x8* p1_ = (u16x8*)((char*)Kt +                                    \
          swz((unsigned)(er*256 + s*32 + 16), (unsigned)er));              \
      u16x8 a0_ = *p0_, a1_ = *p1_, o0_, o1_;                              \
      _Pragma("unroll")                                                    \
      for (int j = 0; j < 8; ++j){                                         \
        o0_[j] = f2b(b2f(a0_[j]) + b2f(V0[j]));                            \
        o1_[j] = f2b(b2f(a1_[j]) + b2f(V1[j]));                            \
      }                                                                    \
      *p0_ = o0_; *p1_ = o1_;                                              \
    }                                                                      \
    bar_lds();                                                             \
    { const int c_ = t & 127, half_ = t >> 7, hh_ = c_ >> 5;               \
      const int eb_ = half_ * 16;                                          \
      float accv_ = 0.f, accd_ = 0.f;                                      \
      int cur_ = rowsT[1 + eb_], rs_ = eb_;                                \
      _Pragma("unroll")                                                    \
      for (int e_ = eb_; e_ < eb_ + 16; ++e_){                             \
        int r_ = rowsT[1 + e_];                                            \
        if (r_ != cur_){                                                   \
          if (cur_ >= 0){                                                  \
            bool own_ = (rowsT[rs_] != cur_) && (rowsT[1 + e_] != cur_);   \
            float* np_ = num + (size_t)cur_*128 + c_;                      \
            if (own_) *np_ = accv_; else atomicAdd(np_, accv_);            \
            if (c_ < 4){                                                   \
              float* dp_ = den + (size_t)cur_*4 + c_;                      \
              if (own_) *dp_ = accd_; else atomicAdd(dp_, accd_);          \
            }                                                              \
          }                                                                \
          cur_ = r_; rs_ = e_; accv_ = 0.f; accd_ = 0.f;                   \
        }                                                                  \
        float a_ = aS[e_][hh_];                                            \
        accv_ += a_ * b2f(*(const unsigned short*)((const char*)Kt +       \
                  swz((unsigned)(e_*256 + c_*2), (unsigned)e_)));          \
        if (c_ < 4) accd_ += aS[e_][c_];                                   \
      }                                                                    \
      if (cur_ >= 0){                                                      \
        bool own_ = (rowsT[rs_] != cur_) && (rowsT[1 + eb_ + 16] != cur_); \
        float* np_ = num + (size_t)cur_*128 + c_;                          \
        if (own_) *np_ = accv_; else atomicAdd(np_, accv_);                \
        if (c_ < 4){                                                       \
          float* dp_ = den + (size_t)cur_*4 + c_;                          \
          if (own_) *dp_ = accd_; else atomicAdd(dp_, accd_);              \
        }                                                                  \
      }                                                                    \
    }                                                                      \
    LOAD_SET(EC, H0,H1,H2,H3, K0,K1,V0,V1);   /* issue data for IT+2 */    \
  } while(0)

  float4 a0, a1, a2, a3, b0v, b1v, b2v, b3v;
  u16x8 ak0, ak1, av0, av1, bk0, bk1, bv0, bv1;
  int4 e0, e1;

  e0 = edata[1 + TILEOF(0)*ET + er];
  e1 = edata[1 + TILEOF(1)*ET + er];
  LOAD_SET(e0, a0, a1, a2, a3, ak0, ak1, av0, av1);
  LOAD_SET(e1, b0v, b1v, b2v, b3v, bk0, bk1, bv0, bv1);

  long it = 0;
  for (; it + 1 < ntloc; it += 2){
    PROC(it,     e0, a0, a1, a2, a3, ak0, ak1, av0, av1);
    PROC(it + 1, e1, b0v, b1v, b2v, b3v, bk0, bk1, bv0, bv1);
  }
  if (it < ntloc)
    PROC(it, e0, a0, a1, a2, a3, ak0, ak1, av0, av1);
#undef PROC
#undef LOAD_SET
#undef TILEOF
}

// ---- fused post: h1 = hV + ssp(num/den/sqrt d)@WO ; out = h1 + FFN(LN2(h1)) ----
__global__ __launch_bounds__(256, 2) void k_post(
    const float* __restrict__ hV, const float* __restrict__ num,
    const float* __restrict__ den,
    const unsigned short* __restrict__ WOT, const unsigned short* __restrict__ WinT,
    const unsigned short* __restrict__ WouT,
    const float* __restrict__ l2s, const float* __restrict__ l2b,
    const float* __restrict__ bin, const float* __restrict__ bou,
    float* __restrict__ out, int N){
  __shared__ unsigned short At[128*128];
  __shared__ float ps[128][2], pq[128][2];
  __shared__ float scs[128], bis[128], binS[128], bouS[128];
  const int t = threadIdx.x;
  if (t < 128){ scs[t] = l2s[t]; bis[t] = l2b[t]; binS[t] = bin[t]; bouS[t] = bou[t]; }
  const int r0 = blockIdx.x * 128;
  const int rl = t & 127, hf = t >> 7;
  const int r = r0 + rl;
  const float inv = 0.17677669529663687f;  // 1/sqrt(32)
  float i0 = 0.f, i1 = 0.f;
  if (r < N){
    float d0 = den[(size_t)r*4 + 2*hf], d1 = den[(size_t)r*4 + 2*hf + 1];
    i0 = (d0 > 0.f) ? inv / d0 : 0.f;
    i1 = (d1 > 0.f) ? inv / d1 : 0.f;
  }
  const float4* ap = (const float4*)(num + (size_t)r*128 + hf*64);
#pragma unroll
  for (int i = 0; i < 8; ++i){
    u16x8 p = {0,0,0,0,0,0,0,0};
    if (r < N){
      float sc = (i < 4) ? i0 : i1;
      float4 v0 = ap[2*i], v1 = ap[2*i+1];
      p[0]=f2b(sspf(v0.x*sc)); p[1]=f2b(sspf(v0.y*sc)); p[2]=f2b(sspf(v0.z*sc)); p[3]=f2b(sspf(v0.w*sc));
      p[4]=f2b(sspf(v1.x*sc)); p[5]=f2b(sspf(v1.y*sc)); p[6]=f2b(sspf(v1.z*sc)); p[7]=f2b(sspf(v1.w*sc));
    }
    *(u16x8*)((char*)At + swz((unsigned)(rl*256 + hf*128 + i*16), (unsigned)rl)) = p;
  }
  __syncthreads();
  const int l = t & 63, wm = (t >> 7) & 1, wn = (t >> 6) & 1;
  f32x4 acc[4][4];
  mma128(At, WOT, t, acc);
  float h1[4][4][4];
#pragma unroll
  for (int m = 0; m < 4; ++m)
#pragma unroll
    for (int reg = 0; reg < 4; ++reg){
      int er = wm*64 + m*16 + ((l >> 4) & 3)*4 + reg;
      int gr = r0 + er;
#pragma unroll
      for (int n = 0; n < 4; ++n){
        int col = wn*64 + n*16 + (l & 15);
        h1[m][n][reg] = acc[m][n][reg] + ((gr < N) ? hV[(size_t)gr*128 + col] : 0.f);
      }
    }
#pragma unroll
  for (int m = 0; m < 4; ++m)
#pragma unroll
    for (int reg = 0; reg < 4; ++reg){
      float s = 0.f, q = 0.f;
#pragma unroll
      for (int n = 0; n < 4; ++n){ float v = h1[m][n][reg]; s += v; q += v*v; }
#pragma unroll
      for (int o = 1; o < 16; o <<= 1){ s += __shfl_xor(s, o); q += __shfl_xor(q, o); }
      if ((l & 15) == 0){
        int er = wm*64 + m*16 + ((l >> 4) & 3)*4 + reg;
        ps[er][wn] = s; pq[er][wn] = q;
      }
    }
  __syncthreads();
#pragma unroll
  for (int m = 0; m < 4; ++m)
#pragma unroll
    for (int reg = 0; reg < 4; ++reg){
      int er = wm*64 + m*16 + ((l >> 4) & 3)*4 + reg;
      float mu  = (ps[er][0] + ps[er][1]) * 0.0078125f;
      float var = (pq[er][0] + pq[er][1]) * 0.0078125f - mu*mu;
      float rsv = rsqrtf(var + 1e-5f);
#pragma unroll
      for (int n = 0; n < 4; ++n){
        int col = wn*64 + n*16 + (l & 15);
        float yv = (h1[m][n][reg] - mu)*rsv*scs[col] + bis[col];
        *(unsigned short*)((char*)At + swz((unsigned)(er*256 + col*2), (unsigned)er)) = f2b(yv);
      }
    }
  __syncthreads();
  mma128(At, WinT, t, acc);
  __syncthreads();
#pragma unroll
  for (int m = 0; m < 4; ++m)
#pragma unroll
    for (int reg = 0; reg < 4; ++reg){
      int er = wm*64 + m*16 + ((l >> 4) & 3)*4 + reg;
#pragma unroll
      for (int n = 0; n < 4; ++n){
        int col = wn*64 + n*16 + (l & 15);
        float v = acc[m][n][reg] + binS[col];
        *(unsigned short*)((char*)At + swz((unsigned)(er*256 + col*2), (unsigned)er))
            = f2b(fmaxf(v, 0.f));
      }
    }
  __syncthreads();
  mma128(At, WouT, t, acc);
#pragma unroll
  for (int m = 0; m < 4; ++m)
#pragma unroll
    for (int reg = 0; reg < 4; ++reg){
      int er = wm*64 + m*16 + ((l >> 4) & 3)*4 + reg;
      int gr = r0 + er;
      if (gr < N){
#pragma unroll
        for (int n = 0; n < 4; ++n){
          int col = wn*64 + n*16 + (l & 15);
          out[(size_t)gr*128 + col] = acc[m][n][reg] + bouS[col] + h1[m][n][reg];
        }
      }
    }
}

extern "C" void kernel_launch(void* const* d_in, const int* in_sizes, int n_in,
                              void* d_out, int out_size, void* d_ws, size_t ws_size,
                              hipStream_t stream)
{
  const float* hV  = (const float*)d_in[0];
  const float* hE  = (const float*)d_in[1];
  const int*   ei  = (const int*)d_in[2];
  const float* WQ  = (const float*)d_in[3];
  const float* WK  = (const float*)d_in[4];
  const float* WV  = (const float*)d_in[5];
  const float* WO  = (const float*)d_in[6];
  const float* l1s = (const float*)d_in[7];
  const float* l1b = (const float*)d_in[8];
  const float* l2s = (const float*)d_in[9];
  const float* l2b = (const float*)d_in[10];
  const float* Wi  = (const float*)d_in[11];
  const float* bi  = (const float*)d_in[12];
  const float* Wo2 = (const float*)d_in[13];
  const float* bo  = (const float*)d_in[14];
  float* out = (float*)d_out;

  const int  N = in_sizes[0] / 128;
  const long E = (long)in_sizes[1] / 128;
  const long NT = (E + ET - 1) / ET;

  char* ws = (char*)d_ws;
  size_t off = 0;
  auto alloc = [&](size_t b){ size_t o = off; off += (b + 255) & ~(size_t)255; return o; };
  const size_t WB = 128*128*sizeof(unsigned short);
  size_t oWQT = alloc(WB), oWKtT = alloc(WB), oWKbT = alloc(WB);
  size_t oWVtT = alloc(WB), oWVbT = alloc(WB), oWOT = alloc(WB);
  size_t oWinT = alloc(WB), oWouT = alloc(WB);
  size_t oQ    = alloc((size_t)N*128*2);
  size_t oYKV  = alloc((size_t)N*256*2);
  size_t oED   = alloc((size_t)(E + 38)*16);
  size_t oCUR  = alloc((size_t)N*4);
  size_t oCNT  = alloc((size_t)N*4);        // zeroed region starts here
  size_t oDEN  = alloc((size_t)N*4*4);
  size_t oNUM  = alloc((size_t)N*128*4);
  size_t zero_bytes = (oNUM + (size_t)N*128*4) - oCNT;

  unsigned short* WQT  = (unsigned short*)(ws + oWQT);
  unsigned short* WKtT = (unsigned short*)(ws + oWKtT);
  unsigned short* WKbT = (unsigned short*)(ws + oWKbT);
  unsigned short* WVtT = (unsigned short*)(ws + oWVtT);
  unsigned short* WVbT = (unsigned short*)(ws + oWVbT);
  unsigned short* WOT  = (unsigned short*)(ws + oWOT);
  unsigned short* WinT = (unsigned short*)(ws + oWinT);
  unsigned short* WouT = (unsigned short*)(ws + oWouT);
  unsigned short* Qbf  = (unsigned short*)(ws + oQ);
  unsigned short* YKVbf= (unsigned short*)(ws + oYKV);
  int4* edata  = (int4*)(ws + oED);
  int* cursor  = (int*)(ws + oCUR);
  int* cnt     = (int*)(ws + oCNT);
  float* den   = (float*)(ws + oDEN);
  float* num   = (float*)(ws + oNUM);

  const int nbN = (N + 127) / 128;
  const int nbe = (int)((E + 255) / 256);
  const int gE  = (int)((NT < 1024) ? NT : 1024);

  k_zero<<<2048, 256, 0, stream>>>((float4*)(ws + oCNT), (long)(zero_bytes / 16));
  k_wprep<<<64, 256, 0, stream>>>(WQ, WK, WV, WO, Wi, Wo2,
                                  WQT, WKtT, WKbT, WVtT, WVbT, WOT, WinT, WouT);
  k_nodeprep<<<nbN, 256, 0, stream>>>(hV, l1s, l1b, WQT, WKbT, WVbT, Qbf, YKVbf, N);
  k_hist<<<nbe, 256, 0, stream>>>(ei, cnt, E, N);
  k_scan<<<1, 1024, 0, stream>>>(cnt, cursor, edata, E, N);
  k_scatter<<<nbe, 256, 0, stream>>>(ei, cursor, edata, E, N);
  k_edge<<<gE, 256, 0, stream>>>(hE, WKtT, WVtT, Qbf, YKVbf,
                                 edata, num, den, E, NT);
  k_post<<<nbN, 256, 0, stream>>>(hV, num, den, WOT, WinT, WouT,
                                  l2s, l2b, bi, bo, out, N);
}

// Round 7
// 917.427 us; speedup vs baseline: 1.8270x; 1.8270x over previous
//
#include <hip/hip_runtime.h>

// Graph-transformer layer, MI355X. N nodes, E edges, H=128, 4 heads x d=32.
// R7: k_edge = 64-edge block tiles, raw-barrier pipeline (lgkmcnt-only +
// s_barrier; global loads stay in flight across barriers), ONE named-reg
// staging set for the hE stream only (32 VGPR, T14 issue-early/write-late);
// YKV/Q synchronous (L2/L3-resident). launch_bounds(256,3) -> VGPR cap 170,
// no spill. ET=64 restores B-fragment amortization (~1.6GB L2).

typedef __bf16 bf16x8 __attribute__((ext_vector_type(8)));
typedef float f32x4 __attribute__((ext_vector_type(4)));
typedef unsigned short u16x8 __attribute__((ext_vector_type(8)));

#define DEV static __device__ __forceinline__
#define ET 64   // edges per k_edge tile

DEV unsigned short f2b(float f){
  union { float f; unsigned u; } v; v.f = f;
  unsigned r = (v.u + 0x7FFFu + ((v.u >> 16) & 1u)) >> 16;   // RNE
  return (unsigned short)r;
}
DEV float b2f(unsigned short h){
  union { unsigned u; float f; } v; v.u = ((unsigned)h) << 16; return v.f;
}
DEV f32x4 mfma16(bf16x8 a, bf16x8 b, f32x4 c){
  return __builtin_amdgcn_mfma_f32_16x16x32_bf16(a, b, c, 0, 0, 0);
}
DEV u16x8 pack8(float4 a, float4 b){
  u16x8 p;
  p[0]=f2b(a.x); p[1]=f2b(a.y); p[2]=f2b(a.z); p[3]=f2b(a.w);
  p[4]=f2b(b.x); p[5]=f2b(b.y); p[6]=f2b(b.z); p[7]=f2b(b.w);
  return p;
}
DEV float sspf(float x){  // shifted softplus
  return fmaxf(x, 0.f) + log1pf(expf(-fabsf(x))) - 0.69314718055994531f;
}
DEV int idx64probe(const int* __restrict__ ei){
  return (ei[1] | ei[3] | ei[5] | ei[7] | ei[9]) == 0;
}
DEV int ld_row(const int* __restrict__ ei, long eg, long E, int is64, int N){
  int v = is64 ? ei[2*eg] : ei[eg];
  return min(max(v, 0), N - 1);
}
DEV int ld_col(const int* __restrict__ ei, long eg, long E, int is64, int N){
  int v = is64 ? ei[2*(E + eg)] : ei[E + eg];
  return min(max(v, 0), N - 1);
}
DEV unsigned swz(unsigned byteoff, unsigned row){
  return byteoff ^ ((row & 7u) << 4);
}
// raw barrier: drain LDS only; global loads stay in flight (counted vmcnt)
DEV void bar_lds(){
  __builtin_amdgcn_sched_barrier(0);
  asm volatile("s_waitcnt lgkmcnt(0)" ::: "memory");
  __builtin_amdgcn_s_barrier();
  __builtin_amdgcn_sched_barrier(0);
}

// ---- 128x128 MFMA tile helper (nodeprep / post): A in LDS (swizzled) ----
DEV void mma128(const unsigned short* At, const unsigned short* __restrict__ WT,
                int t, f32x4 (&acc)[4][4]){
  const int l = t & 63;
  const int wm = (t >> 7) & 1, wn = (t >> 6) & 1;
#pragma unroll
  for (int m = 0; m < 4; ++m)
#pragma unroll
    for (int n = 0; n < 4; ++n)
      acc[m][n] = f32x4{0.f, 0.f, 0.f, 0.f};
#pragma unroll
  for (int kk = 0; kk < 4; ++kk){
    bf16x8 a[4], b[4];
#pragma unroll
    for (int m = 0; m < 4; ++m){
      int row = wm*64 + m*16 + (l & 15);
      a[m] = *(const bf16x8*)((const char*)At +
              swz((unsigned)(row*256 + kk*64 + ((l >> 4) & 3)*16), (unsigned)row));
    }
#pragma unroll
    for (int n = 0; n < 4; ++n){
      int col = wn*64 + n*16 + (l & 15);
      b[n] = *(const bf16x8*)(WT + col*128 + kk*32 + ((l >> 4) & 3)*8);
    }
#pragma unroll
    for (int m = 0; m < 4; ++m)
#pragma unroll
      for (int n = 0; n < 4; ++n)
        acc[m][n] = mfma16(a[m], b[n], acc[m][n]);
  }
}

// ---- 64x128 MFMA (edge tiles): 4 waves 2m x 2n, wave = 32 rows x 64 cols ----
DEV void mma64(const unsigned short* Ab, const unsigned short* __restrict__ WT,
               int t, f32x4 (&acc)[2][4]){
  const int l = t & 63, wid = t >> 6, wm = wid >> 1, wn = wid & 1;
#pragma unroll
  for (int m = 0; m < 2; ++m)
#pragma unroll
    for (int n = 0; n < 4; ++n) acc[m][n] = f32x4{0.f, 0.f, 0.f, 0.f};
#pragma unroll
  for (int kk = 0; kk < 4; ++kk){
    bf16x8 a[2], b[4];
#pragma unroll
    for (int m = 0; m < 2; ++m){
      int row = wm*32 + m*16 + (l & 15);
      a[m] = *(const bf16x8*)((const char*)Ab +
          swz((unsigned)(row*256 + kk*64 + ((l >> 4) & 3)*16), (unsigned)row));
    }
#pragma unroll
    for (int n = 0; n < 4; ++n){
      int col = wn*64 + n*16 + (l & 15);
      b[n] = *(const bf16x8*)(WT + col*128 + kk*32 + ((l >> 4) & 3)*8);
    }
#pragma unroll
    for (int m = 0; m < 2; ++m)
#pragma unroll
      for (int n = 0; n < 4; ++n)
        acc[m][n] = mfma16(a[m], b[n], acc[m][n]);
  }
}
DEV void store_acc64(unsigned short* Kt, const f32x4 (&acc)[2][4], int t){
  const int l = t & 63, wid = t >> 6, wm = wid >> 1, wn = wid & 1;
#pragma unroll
  for (int m = 0; m < 2; ++m)
#pragma unroll
    for (int n = 0; n < 4; ++n)
#pragma unroll
      for (int reg = 0; reg < 4; ++reg){
        int er = wm*32 + m*16 + ((l >> 4) & 3)*4 + reg;
        int col = wn*64 + n*16 + (l & 15);
        *(unsigned short*)((char*)Kt + swz((unsigned)(er*256 + col*2), (unsigned)er))
            = f2b(acc[m][n][reg]);
      }
}

__global__ void k_zero(float4* __restrict__ p, long n){
  long i = (long)blockIdx.x * blockDim.x + threadIdx.x;
  const long st = (long)gridDim.x * blockDim.x;
  const float4 z = {0.f, 0.f, 0.f, 0.f};
  for (; i < n; i += st) p[i] = z;
}

// ---- weight prep: fp32 [k][n] -> bf16 [n][k] blobs ----
__global__ void k_wprep(const float* __restrict__ WQ, const float* __restrict__ WK,
                        const float* __restrict__ WV, const float* __restrict__ WO,
                        const float* __restrict__ Wi, const float* __restrict__ Wo2,
                        unsigned short* WQT, unsigned short* WKtT, unsigned short* WKbT,
                        unsigned short* WVtT, unsigned short* WVbT, unsigned short* WOT,
                        unsigned short* WinT, unsigned short* WouT){
  int id = blockIdx.x * 256 + threadIdx.x;
  int n = id >> 7, k = id & 127;
  int d = n * 128 + k;
  WQT[d]  = f2b(WQ[k*128 + n]);
  WKtT[d] = f2b(WK[k*128 + n]);
  WKbT[d] = f2b(WK[(k+128)*128 + n]);
  WVtT[d] = f2b(WV[k*128 + n]);
  WVbT[d] = f2b(WV[(k+128)*128 + n]);
  WOT[d]  = f2b(WO[k*128 + n]);
  WinT[d] = f2b(Wi[k*128 + n]);
  WouT[d] = f2b(Wo2[k*128 + n]);
}

// ---- counting sort by destination row ----
__global__ void k_hist(const int* __restrict__ ei, int* __restrict__ cnt, long E, int N){
  const int is64 = idx64probe(ei);
  long i = (long)blockIdx.x * blockDim.x + threadIdx.x;
  const long st = (long)gridDim.x * blockDim.x;
  for (; i < E; i += st) atomicAdd(&cnt[ld_row(ei, i, E, is64, N)], 1);
}

DEV int wave_incl_scan(int v, int lane){
#pragma unroll
  for (int ofs = 1; ofs < 64; ofs <<= 1){
    int u = __shfl_up(v, ofs, 64);
    if (lane >= ofs) v += u;
  }
  return v;
}

// chunked exclusive scan: cnt -> cursor; also writes edata sentinels
__global__ __launch_bounds__(1024) void k_scan(const int* __restrict__ cnt,
                                               int* __restrict__ cursor,
                                               int4* __restrict__ edata,
                                               long E, int N){
  __shared__ int wsum[16], woff[16];
  const int t = threadIdx.x, lane = t & 63, w = t >> 6;
  const int C = (N + 1023) / 1024;
  const int base = t * C;
  int s = 0;
  for (int j = 0; j < C; ++j) if (base + j < N) s += cnt[base + j];
  int incl = wave_incl_scan(s, lane);
  if (lane == 63) wsum[w] = incl;
  __syncthreads();
  if (t == 0){
    int run = 0;
#pragma unroll
    for (int i = 0; i < 16; ++i){ woff[i] = run; run += wsum[i]; }
  }
  __syncthreads();
  int run = woff[w] + incl - s;
  for (int j = 0; j < C; ++j)
    if (base + j < N){ cursor[base + j] = run; run += cnt[base + j]; }
  // edata sentinels: [0] and [E+1 .. E+66] get row = -2
  if (t < 67){
    long gi = (t == 0) ? 0 : (E + t);
    edata[gi] = make_int4(0, -2, 0, 0);
  }
}

__global__ void k_scatter(const int* __restrict__ ei, int* __restrict__ cursor,
                          int4* __restrict__ edata, long E, int N){
  const int is64 = idx64probe(ei);
  long i = (long)blockIdx.x * blockDim.x + threadIdx.x;
  const long st = (long)gridDim.x * blockDim.x;
  for (; i < E; i += st){
    int r = ld_row(ei, i, E, is64, N);
    int c = ld_col(ei, i, E, is64, N);
    int pos = atomicAdd(&cursor[r], 1);
    edata[1 + (long)pos] = make_int4((int)i, r, c, 0);
  }
}

// ---- node prep: LN1(h_V) -> y ; Q=y@WQ ; YKV interleaved = {y@WKb, y@WVb} ----
__global__ __launch_bounds__(256) void k_nodeprep(
    const float* __restrict__ hV, const float* __restrict__ l1s, const float* __restrict__ l1b,
    const unsigned short* __restrict__ WQT, const unsigned short* __restrict__ WKbT,
    const unsigned short* __restrict__ WVbT,
    unsigned short* __restrict__ Qbf, unsigned short* __restrict__ YKVbf, int N){
  __shared__ unsigned short At[128*128];
  __shared__ float ps[256], pss[256];
  __shared__ float scs[128], bis[128];
  const int t = threadIdx.x;
  if (t < 128){ scs[t] = l1s[t]; bis[t] = l1b[t]; }
  const int r0 = blockIdx.x * 128;
  const int rl = t & 127, hf = t >> 7;
  const int r = r0 + rl;
  const float4* xp = (const float4*)(hV + (size_t)r*128 + hf*64);
  float s = 0.f, ss = 0.f;
  if (r < N){
#pragma unroll
    for (int i = 0; i < 16; ++i){
      float4 v = xp[i];
      s  += (v.x + v.y) + (v.z + v.w);
      ss += (v.x*v.x + v.y*v.y) + (v.z*v.z + v.w*v.w);
    }
  }
  ps[t] = s; pss[t] = ss;
  __syncthreads();
  const float mu  = (ps[t] + ps[t ^ 128]) * 0.0078125f;
  const float var = (pss[t] + pss[t ^ 128]) * 0.0078125f - mu*mu;
  const float rs  = rsqrtf(var + 1e-5f);
#pragma unroll
  for (int i = 0; i < 8; ++i){
    const int c = hf*64 + i*8;
    u16x8 p = {0,0,0,0,0,0,0,0};
    if (r < N){
      float4 v0 = xp[2*i], v1 = xp[2*i+1];
      p[0] = f2b((v0.x - mu)*rs*scs[c+0] + bis[c+0]);
      p[1] = f2b((v0.y - mu)*rs*scs[c+1] + bis[c+1]);
      p[2] = f2b((v0.z - mu)*rs*scs[c+2] + bis[c+2]);
      p[3] = f2b((v0.w - mu)*rs*scs[c+3] + bis[c+3]);
      p[4] = f2b((v1.x - mu)*rs*scs[c+4] + bis[c+4]);
      p[5] = f2b((v1.y - mu)*rs*scs[c+5] + bis[c+5]);
      p[6] = f2b((v1.z - mu)*rs*scs[c+6] + bis[c+6]);
      p[7] = f2b((v1.w - mu)*rs*scs[c+7] + bis[c+7]);
    }
    *(u16x8*)((char*)At + swz((unsigned)(rl*256 + c*2), (unsigned)rl)) = p;
  }
  __syncthreads();
  const int l = t & 63, wm = (t >> 7) & 1, wn = (t >> 6) & 1;
  f32x4 acc[4][4];
  for (int g = 0; g < 3; ++g){
    const unsigned short* WT = (g == 0) ? WQT : (g == 1) ? WKbT : WVbT;
    mma128(At, WT, t, acc);
#pragma unroll
    for (int m = 0; m < 4; ++m)
#pragma unroll
      for (int reg = 0; reg < 4; ++reg){
        int row = wm*64 + m*16 + ((l >> 4) & 3)*4 + reg;
        int gr = r0 + row;
        if (gr < N){
#pragma unroll
          for (int n = 0; n < 4; ++n){
            int col = wn*64 + n*16 + (l & 15);
            unsigned short v = f2b(acc[m][n][reg]);
            if (g == 0)      Qbf[(size_t)gr*128 + col] = v;
            else if (g == 1) YKVbf[(size_t)gr*256 + col] = v;
            else             YKVbf[(size_t)gr*256 + 128 + col] = v;
          }
        }
      }
  }
}

// ---- persistent fused edge pass: 64-edge tiles, raw-barrier pipeline ----
__global__ __launch_bounds__(256, 3) void k_edge(
    const float* __restrict__ hE,
    const unsigned short* __restrict__ WKtT, const unsigned short* __restrict__ WVtT,
    const unsigned short* __restrict__ Qbf, const unsigned short* __restrict__ YKVbf,
    const int4* __restrict__ edata,     // [1 + E + 67], row sentinels at ends
    float* __restrict__ num, float* __restrict__ den,
    long E, long NT){
  __shared__ unsigned short Ab[ET*128];   // 16KB bf16 swizzled h_E tile
  __shared__ unsigned short Kt[ET*128];   // 16KB (K tile, then V tile)
  __shared__ float aS[ET][4];
  __shared__ int rowsT[2][ET + 2];        // parity-dbuf'd (walk vs next meta)
  __shared__ int colT[2][ET];

  const int t = threadIdx.x;
  const int rr = t & 63, sl = t >> 6;     // staging: row rr, 32-float slice sl
  const long b0 = blockIdx.x, G = gridDim.x;
  const long ntloc = (b0 < NT) ? ((NT - 1 - b0) / G + 1) : 0;
  if (ntloc == 0) return;

  auto tileof = [&](long i) -> long {
    long tt = b0 + i * G; return (tt < NT) ? tt : (NT - 1);
  };

  // prologue: edata(0), hE(0) into named regs; edata(1)
  int4 edc = edata[1 + tileof(0)*ET + rr];
  long pe0 = (long)edc.x; pe0 = pe0 < 0 ? 0 : pe0;
  const float4* hp0 = (const float4*)(hE + (size_t)pe0*128 + sl*32);
  float4 h0=hp0[0], h1=hp0[1], h2=hp0[2], h3=hp0[3],
         h4=hp0[4], h5=hp0[5], h6=hp0[6], h7=hp0[7];
  int4 edn = edata[1 + tileof(1)*ET + rr];

  for (long it = 0; it < ntloc; ++it){
    const int par = (int)(it & 1);
    // phase 0: meta -> LDS; staged regs -> Ab; issue next-tile loads
    if (t < ET){ rowsT[par][1 + t] = edc.y; colT[par][t] = edc.z; }
    if (t == 64) rowsT[par][0]      = edata[tileof(it)*ET].y;            // e0-1
    if (t == 65) rowsT[par][ET + 1] = edata[1 + tileof(it)*ET + ET].y;   // e0+ET
    {
      unsigned base = (unsigned)(rr*256 + sl*64);
      unsigned x = ((unsigned)(rr & 7)) << 4;
      *(u16x8*)((char*)Ab + ((base     ) ^ x)) = pack8(h0, h1);
      *(u16x8*)((char*)Ab + ((base + 16) ^ x)) = pack8(h2, h3);
      *(u16x8*)((char*)Ab + ((base + 32) ^ x)) = pack8(h4, h5);
      *(u16x8*)((char*)Ab + ((base + 48) ^ x)) = pack8(h6, h7);
    }
    edc = edn;
    edn = edata[1 + tileof(it + 2)*ET + rr];
    {
      long pe = (long)edc.x; pe = pe < 0 ? 0 : pe;
      const float4* np = (const float4*)(hE + (size_t)pe*128 + sl*32);
      h0 = np[0]; h1 = np[1]; h2 = np[2]; h3 = np[3];
      h4 = np[4]; h5 = np[5]; h6 = np[6]; h7 = np[7];
    }
    bar_lds();
    // K = hE_tile @ WKtop
    { f32x4 acc[2][4]; mma64(Ab, WKtT, t, acc); store_acc64(Kt, acc, t); }
    bar_lds();
    // logits: edge e = t>>2, head q = t&3 (32 cols each, head-aligned)
    {
      const int e = t >> 2, q = t & 3;
      const int r = rowsT[par][1 + e], c = colT[par][e];
      const int ra = max(r, 0), ca = max(c, 0);
      const u16x8* qp = (const u16x8*)(Qbf  + (size_t)ra*128 + q*32);
      const u16x8* kp = (const u16x8*)(YKVbf + (size_t)ca*256 + q*32);
      const unsigned xb = ((unsigned)(e & 7)) << 4;
      float pl = 0.f;
#pragma unroll
      for (int k = 0; k < 4; ++k){
        u16x8 qv = qp[k], yk = kp[k];
        u16x8 kv = *(const u16x8*)((const char*)Kt +
            (((unsigned)(e*256 + q*64 + k*16)) ^ xb));
#pragma unroll
        for (int j = 0; j < 8; ++j) pl += b2f(qv[j]) * (b2f(kv[j]) + b2f(yk[j]));
      }
      aS[e][q] = (r >= 0) ? expf(pl) : 0.f;
    }
    bar_lds();
    // V = hE_tile @ WVtop (overwrites Kt)
    { f32x4 acc[2][4]; mma64(Ab, WVtT, t, acc); store_acc64(Kt, acc, t); }
    bar_lds();
    // V += YV[col]
    {
      const int e = t >> 2, q = t & 3;
      const int ca = max(colT[par][e], 0);
      const u16x8* vp = (const u16x8*)(YKVbf + (size_t)ca*256 + 128 + q*32);
      const unsigned xb = ((unsigned)(e & 7)) << 4;
#pragma unroll
      for (int k = 0; k < 4; ++k){
        u16x8* pp = (u16x8*)((char*)Kt + (((unsigned)(e*256 + q*64 + k*16)) ^ xb));
        u16x8 a = *pp, b = vp[k], o;
#pragma unroll
        for (int j = 0; j < 8; ++j) o[j] = f2b(b2f(a[j]) + b2f(b[j]));
        *pp = o;
      }
    }
    bar_lds();
    // walk: segment reduce over sorted rows; plain store iff full segment
    {
      const int c = t & 127, half = t >> 7, hh = c >> 5;
      const int eb = half * 32;
      float accv = 0.f, accd = 0.f;
      int cur = rowsT[par][1 + eb], rs = eb;
      for (int e = eb; e < eb + 32; ++e){
        int r = rowsT[par][1 + e];
        if (r != cur){
          if (cur >= 0){
            bool own = (rowsT[par][rs] != cur);   // left-neighbor; right != cur here
            float* np = num + (size_t)cur*128 + c;
            if (own) *np = accv; else atomicAdd(np, accv);
            if (c < 4){
              float* dp = den + (size_t)cur*4 + c;
              if (own) *dp = accd; else atomicAdd(dp, accd);
            }
          }
          cur = r; rs = e; accv = 0.f; accd = 0.f;
        }
        float a = aS[e][hh];
        accv += a * b2f(*(const unsigned short*)((const char*)Kt +
                  swz((unsigned)(e*256 + c*2), (unsigned)e)));
        if (c < 4) accd += aS[e][c];
      }
      if (cur >= 0){
        bool own = (rowsT[par][rs] != cur) && (rowsT[par][1 + eb + 32] != cur);
        float* np = num + (size_t)cur*128 + c;
        if (own) *np = accv; else atomicAdd(np, accv);
        if (c < 4){
          float* dp = den + (size_t)cur*4 + c;
          if (own) *dp = accd; else atomicAdd(dp, accd);
        }
      }
    }
    // no barrier needed: rowsT/colT are parity-dbuf'd; Ab rewritten only in
    // next phase 0, whose readers are gated by the post-phase-0 barrier.
  }
}

// ---- fused post: h1 = hV + ssp(num/den/sqrt d)@WO ; out = h1 + FFN(LN2(h1)) ----
__global__ __launch_bounds__(256, 2) void k_post(
    const float* __restrict__ hV, const float* __restrict__ num,
    const float* __restrict__ den,
    const unsigned short* __restrict__ WOT, const unsigned short* __restrict__ WinT,
    const unsigned short* __restrict__ WouT,
    const float* __restrict__ l2s, const float* __restrict__ l2b,
    const float* __restrict__ bin, const float* __restrict__ bou,
    float* __restrict__ out, int N){
  __shared__ unsigned short At[128*128];
  __shared__ float ps[128][2], pq[128][2];
  __shared__ float scs[128], bis[128], binS[128], bouS[128];
  const int t = threadIdx.x;
  if (t < 128){ scs[t] = l2s[t]; bis[t] = l2b[t]; binS[t] = bin[t]; bouS[t] = bou[t]; }
  const int r0 = blockIdx.x * 128;
  const int rl = t & 127, hf = t >> 7;
  const int r = r0 + rl;
  const float inv = 0.17677669529663687f;  // 1/sqrt(32)
  float i0 = 0.f, i1 = 0.f;
  if (r < N){
    float d0 = den[(size_t)r*4 + 2*hf], d1 = den[(size_t)r*4 + 2*hf + 1];
    i0 = (d0 > 0.f) ? inv / d0 : 0.f;
    i1 = (d1 > 0.f) ? inv / d1 : 0.f;
  }
  const float4* ap = (const float4*)(num + (size_t)r*128 + hf*64);
#pragma unroll
  for (int i = 0; i < 8; ++i){
    u16x8 p = {0,0,0,0,0,0,0,0};
    if (r < N){
      float sc = (i < 4) ? i0 : i1;
      float4 v0 = ap[2*i], v1 = ap[2*i+1];
      p[0]=f2b(sspf(v0.x*sc)); p[1]=f2b(sspf(v0.y*sc)); p[2]=f2b(sspf(v0.z*sc)); p[3]=f2b(sspf(v0.w*sc));
      p[4]=f2b(sspf(v1.x*sc)); p[5]=f2b(sspf(v1.y*sc)); p[6]=f2b(sspf(v1.z*sc)); p[7]=f2b(sspf(v1.w*sc));
    }
    *(u16x8*)((char*)At + swz((unsigned)(rl*256 + hf*128 + i*16), (unsigned)rl)) = p;
  }
  __syncthreads();
  const int l = t & 63, wm = (t >> 7) & 1, wn = (t >> 6) & 1;
  f32x4 acc[4][4];
  mma128(At, WOT, t, acc);
  float h1[4][4][4];
#pragma unroll
  for (int m = 0; m < 4; ++m)
#pragma unroll
    for (int reg = 0; reg < 4; ++reg){
      int er = wm*64 + m*16 + ((l >> 4) & 3)*4 + reg;
      int gr = r0 + er;
#pragma unroll
      for (int n = 0; n < 4; ++n){
        int col = wn*64 + n*16 + (l & 15);
        h1[m][n][reg] = acc[m][n][reg] + ((gr < N) ? hV[(size_t)gr*128 + col] : 0.f);
      }
    }
#pragma unroll
  for (int m = 0; m < 4; ++m)
#pragma unroll
    for (int reg = 0; reg < 4; ++reg){
      float s = 0.f, q = 0.f;
#pragma unroll
      for (int n = 0; n < 4; ++n){ float v = h1[m][n][reg]; s += v; q += v*v; }
#pragma unroll
      for (int o = 1; o < 16; o <<= 1){ s += __shfl_xor(s, o); q += __shfl_xor(q, o); }
      if ((l & 15) == 0){
        int er = wm*64 + m*16 + ((l >> 4) & 3)*4 + reg;
        ps[er][wn] = s; pq[er][wn] = q;
      }
    }
  __syncthreads();
#pragma unroll
  for (int m = 0; m < 4; ++m)
#pragma unroll
    for (int reg = 0; reg < 4; ++reg){
      int er = wm*64 + m*16 + ((l >> 4) & 3)*4 + reg;
      float mu  = (ps[er][0] + ps[er][1]) * 0.0078125f;
      float var = (pq[er][0] + pq[er][1]) * 0.0078125f - mu*mu;
      float rsv = rsqrtf(var + 1e-5f);
#pragma unroll
      for (int n = 0; n < 4; ++n){
        int col = wn*64 + n*16 + (l & 15);
        float yv = (h1[m][n][reg] - mu)*rsv*scs[col] + bis[col];
        *(unsigned short*)((char*)At + swz((unsigned)(er*256 + col*2), (unsigned)er)) = f2b(yv);
      }
    }
  __syncthreads();
  mma128(At, WinT, t, acc);
  __syncthreads();
#pragma unroll
  for (int m = 0; m < 4; ++m)
#pragma unroll
    for (int reg = 0; reg < 4; ++reg){
      int er = wm*64 + m*16 + ((l >> 4) & 3)*4 + reg;
#pragma unroll
      for (int n = 0; n < 4; ++n){
        int col = wn*64 + n*16 + (l & 15);
        float v = acc[m][n][reg] + binS[col];
        *(unsigned short*)((char*)At + swz((unsigned)(er*256 + col*2), (unsigned)er))
            = f2b(fmaxf(v, 0.f));
      }
    }
  __syncthreads();
  mma128(At, WouT, t, acc);
#pragma unroll
  for (int m = 0; m < 4; ++m)
#pragma unroll
    for (int reg = 0; reg < 4; ++reg){
      int er = wm*64 + m*16 + ((l >> 4) & 3)*4 + reg;
      int gr = r0 + er;
      if (gr < N){
#pragma unroll
        for (int n = 0; n < 4; ++n){
          int col = wn*64 + n*16 + (l & 15);
          out[(size_t)gr*128 + col] = acc[m][n][reg] + bouS[col] + h1[m][n][reg];
        }
      }
    }
}

extern "C" void kernel_launch(void* const* d_in, const int* in_sizes, int n_in,
                              void* d_out, int out_size, void* d_ws, size_t ws_size,
                              hipStream_t stream)
{
  const float* hV  = (const float*)d_in[0];
  const float* hE  = (const float*)d_in[1];
  const int*   ei  = (const int*)d_in[2];
  const float* WQ  = (const float*)d_in[3];
  const float* WK  = (const float*)d_in[4];
  const float* WV  = (const float*)d_in[5];
  const float* WO  = (const float*)d_in[6];
  const float* l1s = (const float*)d_in[7];
  const float* l1b = (const float*)d_in[8];
  const float* l2s = (const float*)d_in[9];
  const float* l2b = (const float*)d_in[10];
  const float* Wi  = (const float*)d_in[11];
  const float* bi  = (const float*)d_in[12];
  const float* Wo2 = (const float*)d_in[13];
  const float* bo  = (const float*)d_in[14];
  float* out = (float*)d_out;

  const int  N = in_sizes[0] / 128;
  const long E = (long)in_sizes[1] / 128;
  const long NT = (E + ET - 1) / ET;

  char* ws = (char*)d_ws;
  size_t off = 0;
  auto alloc = [&](size_t b){ size_t o = off; off += (b + 255) & ~(size_t)255; return o; };
  const size_t WB = 128*128*sizeof(unsigned short);
  size_t oWQT = alloc(WB), oWKtT = alloc(WB), oWKbT = alloc(WB);
  size_t oWVtT = alloc(WB), oWVbT = alloc(WB), oWOT = alloc(WB);
  size_t oWinT = alloc(WB), oWouT = alloc(WB);
  size_t oQ    = alloc((size_t)N*128*2);
  size_t oYKV  = alloc((size_t)N*256*2);
  size_t oED   = alloc((size_t)(E + 70)*16);
  size_t oCUR  = alloc((size_t)N*4);
  size_t oCNT  = alloc((size_t)N*4);        // zeroed region starts here
  size_t oDEN  = alloc((size_t)N*4*4);
  size_t oNUM  = alloc((size_t)N*128*4);
  size_t zero_bytes = (oNUM + (size_t)N*128*4) - oCNT;

  unsigned short* WQT  = (unsigned short*)(ws + oWQT);
  unsigned short* WKtT = (unsigned short*)(ws + oWKtT);
  unsigned short* WKbT = (unsigned short*)(ws + oWKbT);
  unsigned short* WVtT = (unsigned short*)(ws + oWVtT);
  unsigned short* WVbT = (unsigned short*)(ws + oWVbT);
  unsigned short* WOT  = (unsigned short*)(ws + oWOT);
  unsigned short* WinT = (unsigned short*)(ws + oWinT);
  unsigned short* WouT = (unsigned short*)(ws + oWouT);
  unsigned short* Qbf  = (unsigned short*)(ws + oQ);
  unsigned short* YKVbf= (unsigned short*)(ws + oYKV);
  int4* edata  = (int4*)(ws + oED);
  int* cursor  = (int*)(ws + oCUR);
  int* cnt     = (int*)(ws + oCNT);
  float* den   = (float*)(ws + oDEN);
  float* num   = (float*)(ws + oNUM);

  const int nbN = (N + 127) / 128;
  const int nbe = (int)((E + 255) / 256);
  const int gE  = (int)((NT < 768) ? NT : 768);

  k_zero<<<2048, 256, 0, stream>>>((float4*)(ws + oCNT), (long)(zero_bytes / 16));
  k_wprep<<<64, 256, 0, stream>>>(WQ, WK, WV, WO, Wi, Wo2,
                                  WQT, WKtT, WKbT, WVtT, WVbT, WOT, WinT, WouT);
  k_nodeprep<<<nbN, 256, 0, stream>>>(hV, l1s, l1b, WQT, WKbT, WVbT, Qbf, YKVbf, N);
  k_hist<<<nbe, 256, 0, stream>>>(ei, cnt, E, N);
  k_scan<<<1, 1024, 0, stream>>>(cnt, cursor, edata, E, N);
  k_scatter<<<nbe, 256, 0, stream>>>(ei, cursor, edata, E, N);
  k_edge<<<gE, 256, 0, stream>>>(hE, WKtT, WVtT, Qbf, YKVbf,
                                 edata, num, den, E, NT);
  k_post<<<nbN, 256, 0, stream>>>(hV, num, den, WOT, WinT, WouT,
                                  l2s, l2b, bi, bo, out, N);
}